// Round 1
// baseline (207.783 us; speedup 1.0000x reference)
//
#include <hip/hip_runtime.h>
#include <hip/hip_bf16.h>
#include <cstddef>

#define B_ 8
#define C_ 2048
#define E_ 256
#define H_ 64
#define T_ 512
#define NA 4
#define KAPPA 0.9f

// ---------------- Projection GEMM: [16384,256] @ [256,64] -> [16384,64] ----
// grid (M/64, 3), block 256. blockIdx.y selects (query@w_q, key@w_k, value@w_v).
__global__ __launch_bounds__(256) void proj_kernel(
    const float* __restrict__ key_in, const float* __restrict__ query,
    const float* __restrict__ value,
    const float* __restrict__ w_q, const float* __restrict__ w_k,
    const float* __restrict__ w_v,
    float* __restrict__ qp, float* __restrict__ kp, float* __restrict__ vp)
{
    const float* A; const float* W; float* O;
    if (blockIdx.y == 0)      { A = query;  W = w_q; O = qp; }
    else if (blockIdx.y == 1) { A = key_in; W = w_k; O = kp; }
    else                      { A = value;  W = w_v; O = vp; }

    __shared__ float As[64][65];
    __shared__ float Ws[64][65];

    const int row0 = blockIdx.x * 64;
    const int col  = threadIdx.x & 63;
    const int g    = threadIdx.x >> 6;   // 0..3

    float acc[16];
#pragma unroll
    for (int i = 0; i < 16; ++i) acc[i] = 0.f;

    for (int k0 = 0; k0 < E_; k0 += 64) {
        __syncthreads();
#pragma unroll
        for (int i = 0; i < 16; ++i) {
            int idx = i * 256 + threadIdx.x;
            int r = idx >> 6, cc = idx & 63;
            As[r][cc] = A[(size_t)(row0 + r) * E_ + k0 + cc];
            Ws[r][cc] = W[(size_t)(k0 + r) * H_ + cc];
        }
        __syncthreads();
#pragma unroll
        for (int kk = 0; kk < 64; ++kk) {
            float wv = Ws[kk][col];
#pragma unroll
            for (int i = 0; i < 16; ++i)
                acc[i] += As[g + 4 * i][kk] * wv;
        }
    }
#pragma unroll
    for (int i = 0; i < 16; ++i)
        O[(size_t)(row0 + g + 4 * i) * H_ + col] = acc[i];
}

// ---------------- Dones scan -----------------------------------------------
// One block. Detects whether dones arrive as 1-byte bool or int32 (values
// 0/1, little-endian): if any byte at offset %4 != 0 within the first
// B_*C_ bytes is nonzero, layout is 1-byte; else treat as int32.
__global__ void dones_kernel(const unsigned char* __restrict__ raw,
                             int* __restrict__ lastdone,
                             int* __restrict__ firstdone,
                             float* __restrict__ delta)
{
    __shared__ int flag;
    if (threadIdx.x == 0) flag = 0;
    __syncthreads();
    for (int j = threadIdx.x; j < B_ * C_; j += blockDim.x) {
        if ((j & 3) != 0 && raw[j] != 0) flag = 1;
    }
    __syncthreads();
    const int stride = flag ? 1 : 4;

    if (threadIdx.x < B_) {
        int b = threadIdx.x;
        int cs = 0, last = 0, firstI = T_;
        for (int i = 0; i < T_; ++i) {
            unsigned char v = raw[(size_t)(b * C_ + NA * i) * stride];
            int tsv = (v != 0);
            cs += tsv;
            if (tsv) { last = i; if (firstI == T_) firstI = i; }
            lastdone[b * T_ + i] = last;   // segment start s(n)
        }
        firstdone[b] = firstI;
        delta[b] = (cs == 0) ? 1.f : 0.f;
    }
}

// ---------------- out0 = inner + cross --------------------------------------
// grid B*T blocks, 256 threads = 4 waves; wave ca handles row c = 4n+ca,
// lane d owns output dim d. Segment-limited score*V accumulation.
__global__ __launch_bounds__(256) void out0_kernel(
    const float* __restrict__ qp, const float* __restrict__ kp,
    const float* __restrict__ vp, const float* __restrict__ hs,
    const int* __restrict__ lastdone, const int* __restrict__ firstdone,
    float* __restrict__ out0)
{
    const int n  = blockIdx.x & (T_ - 1);
    const int b  = blockIdx.x >> 9;
    const int ca = threadIdx.x >> 6;
    const int d  = threadIdx.x & 63;
    const int c  = NA * n + ca;

    const float* kb = kp + (size_t)b * C_ * H_;
    const float* vb = vp + (size_t)b * C_ * H_;
    const float qv  = qp[((size_t)b * C_ + c) * H_ + d];

    float acc = 0.f;
    // diagonal timestep block: m = 4n+ma, ma <= ca, decay = 1
    for (int ma = 0; ma <= ca; ++ma) {
        int m = NA * n + ma;
        float prod = qv * kb[(size_t)m * H_ + d];
#pragma unroll
        for (int off = 32; off; off >>= 1) prod += __shfl_xor(prod, off);
        acc += prod * vb[(size_t)m * H_ + d];
    }
    // earlier timesteps in the same segment
    const int s = lastdone[b * T_ + n];
    float decay = KAPPA;
    for (int mt = n - 1; mt >= s; --mt) {
#pragma unroll
        for (int ma = 0; ma < NA; ++ma) {
            int m = NA * mt + ma;
            float prod = qv * kb[(size_t)m * H_ + d];
#pragma unroll
            for (int off = 32; off; off >>= 1) prod += __shfl_xor(prod, off);
            acc += decay * prod * vb[(size_t)m * H_ + d];
        }
        decay *= KAPPA;
    }
    // cross = (q @ hstate) * xi ; q row is distributed across lanes
    float cacc = 0.f;
    const float* hsb = hs + (size_t)b * H_ * H_;
#pragma unroll
    for (int h = 0; h < H_; ++h) {
        float qh = __shfl(qv, h);
        cacc += qh * hsb[h * H_ + d];
    }
    const float xi = (n < firstdone[b]) ? powf(KAPPA, (float)(n + 1)) : 0.f;
    out0[((size_t)b * C_ + c) * H_ + d] = acc + xi * cacc;
}

// ---------------- next_h ----------------------------------------------------
// grid B*H blocks of 64 threads. next_h[b,h,d] = sum over last segment of
// kappa^(T-1-mt) * k[m,h] * v[m,d]  +  hstate*kappa^T*delta.
__global__ __launch_bounds__(64) void nexth_kernel(
    const float* __restrict__ kp, const float* __restrict__ vp,
    const float* __restrict__ hs, const int* __restrict__ lastdone,
    const float* __restrict__ delta, float* __restrict__ outh)
{
    const int h = blockIdx.x & (H_ - 1);
    const int b = blockIdx.x >> 6;
    const int d = threadIdx.x;
    const int s = lastdone[b * T_ + (T_ - 1)];
    const float* kb = kp + (size_t)b * C_ * H_;
    const float* vb = vp + (size_t)b * C_ * H_;

    float acc = 0.f;
    float w = 1.f;
    for (int mt = T_ - 1; mt >= s; --mt) {
#pragma unroll
        for (int ma = 0; ma < NA; ++ma) {
            int m = NA * mt + ma;
            acc += w * kb[(size_t)m * H_ + h] * vb[(size_t)m * H_ + d];
        }
        w *= KAPPA;
    }
    acc += hs[(size_t)b * H_ * H_ + h * H_ + d] * powf(KAPPA, (float)T_) * delta[b];
    outh[(size_t)b * H_ * H_ + h * H_ + d] = acc;
}

extern "C" void kernel_launch(void* const* d_in, const int* in_sizes, int n_in,
                              void* d_out, int out_size, void* d_ws, size_t ws_size,
                              hipStream_t stream)
{
    const float* key_in = (const float*)d_in[0];
    const float* query  = (const float*)d_in[1];
    const float* value  = (const float*)d_in[2];
    const float* hstate = (const float*)d_in[3];
    const unsigned char* dones = (const unsigned char*)d_in[4];
    const float* w_q = (const float*)d_in[5];
    const float* w_k = (const float*)d_in[6];
    const float* w_v = (const float*)d_in[7];

    float* qp = (float*)d_ws;
    float* kp = qp + (size_t)B_ * C_ * H_;
    float* vp = kp + (size_t)B_ * C_ * H_;
    int*   lastdone  = (int*)(vp + (size_t)B_ * C_ * H_);
    int*   firstdone = lastdone + B_ * T_;
    float* delta     = (float*)(firstdone + B_);

    dim3 pgrid(B_ * C_ / 64, 3);
    proj_kernel<<<pgrid, 256, 0, stream>>>(key_in, query, value,
                                           w_q, w_k, w_v, qp, kp, vp);
    dones_kernel<<<1, 256, 0, stream>>>(dones, lastdone, firstdone, delta);
    out0_kernel<<<B_ * T_, 256, 0, stream>>>(qp, kp, vp, hstate,
                                             lastdone, firstdone, (float*)d_out);
    nexth_kernel<<<B_ * H_, 64, 0, stream>>>(kp, vp, hstate, lastdone, delta,
                                             (float*)d_out + (size_t)B_ * C_ * H_);
}

// Round 2
// 51.262 us; speedup vs baseline: 4.0534x; 4.0534x over previous
//
#include <hip/hip_runtime.h>
#include <hip/hip_bf16.h>
#include <cstddef>

#define B_ 8
#define C_ 2048
#define E_ 256
#define H_ 64
#define T_ 512
#define NA 4
#define KAPPA 0.9f

typedef __attribute__((ext_vector_type(8))) short bf16x8;
typedef __attribute__((ext_vector_type(4))) float f32x4;

__device__ inline short f2bf(float x) {
    unsigned u = __builtin_bit_cast(unsigned, x);
    u += 0x7fff + ((u >> 16) & 1);   // RNE
    return (short)(u >> 16);
}

// ---------------- W transpose+convert: W[256][64] f32 -> Wt[64][256] bf16 ---
// grid 12 blocks: mat = bid>>2, k-chunk of 64 = bid&3.
__global__ __launch_bounds__(256) void wt_kernel(
    const float* __restrict__ w_q, const float* __restrict__ w_k,
    const float* __restrict__ w_v, short* __restrict__ wt)
{
    const int mat = blockIdx.x >> 2;
    const int k0  = (blockIdx.x & 3) * 64;
    const float* W = (mat == 0) ? w_q : (mat == 1) ? w_k : w_v;
    __shared__ float tile[64][67];
    const int t = threadIdx.x;
#pragma unroll
    for (int pass = 0; pass < 16; ++pass) {
        int idx = pass * 256 + t;
        int r = idx >> 6, c = idx & 63;
        tile[r][c] = W[(size_t)(k0 + r) * H_ + c];
    }
    __syncthreads();
#pragma unroll
    for (int pass = 0; pass < 16; ++pass) {
        int idx = pass * 256 + t;
        int d = idx >> 6, c = idx & 63;  // c = k offset within chunk
        wt[(size_t)mat * (H_ * E_) + (size_t)d * E_ + k0 + c] = f2bf(tile[c][d]);
    }
}

// ---------------- Projection GEMM via MFMA ----------------------------------
// [16384,256] f32 @ Wt^T (bf16) -> [16384,64] f32. grid (256, 3), block 256.
// Block = 64 output rows; wave mt owns 16 rows x all 64 cols (4 n-tiles).
__global__ __launch_bounds__(256) void proj_mfma(
    const float* __restrict__ key_in, const float* __restrict__ query,
    const float* __restrict__ value, const short* __restrict__ wt,
    float* __restrict__ qp, float* __restrict__ kp, float* __restrict__ vp)
{
    const int mat = blockIdx.y;
    const float* A; float* O;
    if (mat == 0)      { A = query;  O = qp; }
    else if (mat == 1) { A = key_in; O = kp; }
    else               { A = value;  O = vp; }

    __shared__ short Wt[64][264];  // [d][k], pad 264 (16B-aligned rows, 2-way banks)
    __shared__ short At[64][40];   // [row][k-chunk 32 + pad]

    const int t    = threadIdx.x;
    const int row0 = blockIdx.x * 64;
    const int lane = t & 63;
    const int mt   = t >> 6;       // wave id = m-tile
    const int lr   = lane & 15;
    const int lg   = lane >> 4;

    const short* wsrc = wt + (size_t)mat * (H_ * E_);
#pragma unroll
    for (int pass = 0; pass < 8; ++pass) {
        int idx = pass * 2048 + t * 8;
        int d = idx >> 8, k = idx & 255;
        *(bf16x8*)&Wt[d][k] = *(const bf16x8*)&wsrc[idx];
    }

    f32x4 acc[4] = {};

    const int r  = t >> 2;          // staging row
    const int kk = (t & 3) * 8;     // staging k offset
    for (int kc = 0; kc < 8; ++kc) {
        __syncthreads();
        {   // stage 64x32 f32 chunk -> bf16 LDS
            const float* src = &A[(size_t)(row0 + r) * E_ + kc * 32 + kk];
            f32x4 x0 = *(const f32x4*)src;
            f32x4 x1 = *(const f32x4*)(src + 4);
            bf16x8 bv;
            bv[0] = f2bf(x0[0]); bv[1] = f2bf(x0[1]);
            bv[2] = f2bf(x0[2]); bv[3] = f2bf(x0[3]);
            bv[4] = f2bf(x1[0]); bv[5] = f2bf(x1[1]);
            bv[6] = f2bf(x1[2]); bv[7] = f2bf(x1[3]);
            *(bf16x8*)&At[r][kk] = bv;
        }
        __syncthreads();
        bf16x8 afrag = *(const bf16x8*)&At[mt * 16 + lr][lg * 8];
#pragma unroll
        for (int nt = 0; nt < 4; ++nt) {
            bf16x8 bfrag = *(const bf16x8*)&Wt[nt * 16 + lr][kc * 32 + lg * 8];
            acc[nt] = __builtin_amdgcn_mfma_f32_16x16x32_bf16(afrag, bfrag, acc[nt], 0, 0, 0);
        }
    }

#pragma unroll
    for (int nt = 0; nt < 4; ++nt)
#pragma unroll
        for (int i = 0; i < 4; ++i)
            O[(size_t)(row0 + mt * 16 + lg * 4 + i) * H_ + nt * 16 + lr] = acc[nt][i];
}

// ---------------- Dones scan (parallel) -------------------------------------
// grid B_, block T_=512. Hillis-Steele inclusive max-scan for lastdone.
__global__ __launch_bounds__(512) void dones_kernel(
    const unsigned char* __restrict__ raw,
    int* __restrict__ lastdone, int* __restrict__ firstdone,
    float* __restrict__ delta)
{
    __shared__ int flag;
    __shared__ int firstsh;
    __shared__ int arr[T_];
    const int b = blockIdx.x;
    const int n = threadIdx.x;
    if (n == 0) { flag = 0; firstsh = T_; }
    __syncthreads();
    // layout detection: bool (1B) vs int32 (4B little-endian 0/1)
    for (int j = n; j < B_ * C_; j += T_)
        if ((j & 3) != 0 && raw[j] != 0) flag = 1;
    __syncthreads();
    const int stride = flag ? 1 : 4;

    int done = raw[(size_t)(b * C_ + NA * n) * stride] != 0;
    arr[n] = done ? n : 0;
    if (done) atomicMin(&firstsh, n);
    __syncthreads();
    for (int off = 1; off < T_; off <<= 1) {
        int v = (n >= off) ? arr[n - off] : 0;
        __syncthreads();
        if (v > arr[n]) arr[n] = v;
        __syncthreads();
    }
    lastdone[b * T_ + n] = arr[n];
    if (n == 0) {
        firstdone[b] = firstsh;
        delta[b] = (firstsh == T_) ? 1.f : 0.f;
    }
}

// ---------------- out0 = inner + cross --------------------------------------
__global__ __launch_bounds__(256) void out0_kernel(
    const float* __restrict__ qp, const float* __restrict__ kp,
    const float* __restrict__ vp, const float* __restrict__ hs,
    const int* __restrict__ lastdone, const int* __restrict__ firstdone,
    float* __restrict__ out0)
{
    const int n  = blockIdx.x & (T_ - 1);
    const int b  = blockIdx.x >> 9;
    const int ca = threadIdx.x >> 6;
    const int d  = threadIdx.x & 63;
    const int c  = NA * n + ca;

    const float* kb = kp + (size_t)b * C_ * H_;
    const float* vb = vp + (size_t)b * C_ * H_;
    const float qv  = qp[((size_t)b * C_ + c) * H_ + d];

    float acc = 0.f;
    for (int ma = 0; ma <= ca; ++ma) {
        int m = NA * n + ma;
        float prod = qv * kb[(size_t)m * H_ + d];
#pragma unroll
        for (int off = 32; off; off >>= 1) prod += __shfl_xor(prod, off);
        acc += prod * vb[(size_t)m * H_ + d];
    }
    const int s = lastdone[b * T_ + n];
    float decay = KAPPA;
    for (int mt = n - 1; mt >= s; --mt) {
#pragma unroll
        for (int ma = 0; ma < NA; ++ma) {
            int m = NA * mt + ma;
            float prod = qv * kb[(size_t)m * H_ + d];
#pragma unroll
            for (int off = 32; off; off >>= 1) prod += __shfl_xor(prod, off);
            acc += decay * prod * vb[(size_t)m * H_ + d];
        }
        decay *= KAPPA;
    }
    // cross term only when xi != 0 (n < firstdone)
    if (n < firstdone[b]) {
        float cacc = 0.f;
        const float* hsb = hs + (size_t)b * H_ * H_;
#pragma unroll
        for (int h = 0; h < H_; ++h) {
            float qh = __shfl(qv, h);
            cacc += qh * hsb[h * H_ + d];
        }
        acc += powf(KAPPA, (float)(n + 1)) * cacc;
    }
    out0[((size_t)b * C_ + c) * H_ + d] = acc;
}

// ---------------- next_h ----------------------------------------------------
__global__ __launch_bounds__(64) void nexth_kernel(
    const float* __restrict__ kp, const float* __restrict__ vp,
    const float* __restrict__ hs, const int* __restrict__ lastdone,
    const float* __restrict__ delta, float* __restrict__ outh)
{
    const int h = blockIdx.x & (H_ - 1);
    const int b = blockIdx.x >> 6;
    const int d = threadIdx.x;
    const int s = lastdone[b * T_ + (T_ - 1)];
    const float* kb = kp + (size_t)b * C_ * H_;
    const float* vb = vp + (size_t)b * C_ * H_;

    float acc = 0.f;
    float w = 1.f;
    for (int mt = T_ - 1; mt >= s; --mt) {
#pragma unroll
        for (int ma = 0; ma < NA; ++ma) {
            int m = NA * mt + ma;
            acc += w * kb[(size_t)m * H_ + h] * vb[(size_t)m * H_ + d];
        }
        w *= KAPPA;
    }
    acc += hs[(size_t)b * H_ * H_ + h * H_ + d] * powf(KAPPA, (float)T_) * delta[b];
    outh[(size_t)b * H_ * H_ + h * H_ + d] = acc;
}

extern "C" void kernel_launch(void* const* d_in, const int* in_sizes, int n_in,
                              void* d_out, int out_size, void* d_ws, size_t ws_size,
                              hipStream_t stream)
{
    const float* key_in = (const float*)d_in[0];
    const float* query  = (const float*)d_in[1];
    const float* value  = (const float*)d_in[2];
    const float* hstate = (const float*)d_in[3];
    const unsigned char* dones = (const unsigned char*)d_in[4];
    const float* w_q = (const float*)d_in[5];
    const float* w_k = (const float*)d_in[6];
    const float* w_v = (const float*)d_in[7];

    float* qp = (float*)d_ws;
    float* kp = qp + (size_t)B_ * C_ * H_;
    float* vp = kp + (size_t)B_ * C_ * H_;
    short* wt = (short*)(vp + (size_t)B_ * C_ * H_);
    int*   lastdone  = (int*)(wt + 3 * H_ * E_);
    int*   firstdone = lastdone + B_ * T_;
    float* delta     = (float*)(firstdone + B_);

    wt_kernel<<<12, 256, 0, stream>>>(w_q, w_k, w_v, wt);
    dones_kernel<<<B_, T_, 0, stream>>>(dones, lastdone, firstdone, delta);
    dim3 pgrid(B_ * C_ / 64, 3);
    proj_mfma<<<pgrid, 256, 0, stream>>>(key_in, query, value, wt, qp, kp, vp);
    out0_kernel<<<B_ * T_, 256, 0, stream>>>(qp, kp, vp, hstate,
                                             lastdone, firstdone, (float*)d_out);
    nexth_kernel<<<B_ * H_, 64, 0, stream>>>(kp, vp, hstate, lastdone, delta,
                                             (float*)d_out + (size_t)B_ * C_ * H_);
}

// Round 3
// 43.232 us; speedup vs baseline: 4.8063x; 1.1857x over previous
//
#include <hip/hip_runtime.h>
#include <hip/hip_bf16.h>
#include <cstddef>

#define B_ 8
#define C_ 2048
#define E_ 256
#define H_ 64
#define T_ 512
#define NA 4
#define KAPPA 0.9f

typedef __attribute__((ext_vector_type(8))) short bf16x8;
typedef __attribute__((ext_vector_type(4))) float f32x4;

__device__ inline short f2bf(float x) {
    unsigned u = __builtin_bit_cast(unsigned, x);
    u += 0x7fff + ((u >> 16) & 1);   // RNE
    return (short)(u >> 16);
}

// ---------------- prep: W transpose (blocks 0-11) + dones scan (12-19) ------
__global__ __launch_bounds__(512) void prep_kernel(
    const float* __restrict__ w_q, const float* __restrict__ w_k,
    const float* __restrict__ w_v, short* __restrict__ wt,
    const unsigned char* __restrict__ raw,
    int* __restrict__ lastdone, int* __restrict__ firstdone,
    float* __restrict__ delta)
{
    __shared__ float tile[64][65];
    __shared__ int arr[T_];
    __shared__ int flag, firstsh;
    const int t = threadIdx.x;

    if (blockIdx.x < 12) {
        // W[256][64] f32 -> Wt[64][256] bf16, one 64x64 chunk per block
        const int mat = blockIdx.x >> 2;
        const int k0  = (blockIdx.x & 3) * 64;
        const float* W = (mat == 0) ? w_q : (mat == 1) ? w_k : w_v;
#pragma unroll
        for (int pass = 0; pass < 8; ++pass) {
            int idx = pass * 512 + t;
            int r = idx >> 6, c = idx & 63;
            tile[r][c] = W[(size_t)(k0 + r) * H_ + c];
        }
        __syncthreads();
#pragma unroll
        for (int pass = 0; pass < 8; ++pass) {
            int idx = pass * 512 + t;
            int d = idx >> 6, c = idx & 63;
            wt[(size_t)mat * (H_ * E_) + (size_t)d * E_ + k0 + c] = f2bf(tile[c][d]);
        }
    } else {
        // dones scan for batch b
        const int b = blockIdx.x - 12;
        const int n = t;
        if (n == 0) { flag = 0; firstsh = T_; }
        __syncthreads();
        // layout detection: bool (1B) vs int32 (4B little-endian 0/1)
        for (int j = n; j < B_ * C_; j += T_)
            if ((j & 3) != 0 && raw[j] != 0) flag = 1;
        __syncthreads();
        const int stride = flag ? 1 : 4;

        int done = raw[(size_t)(b * C_ + NA * n) * stride] != 0;
        arr[n] = done ? n : 0;
        if (done) atomicMin(&firstsh, n);
        __syncthreads();
        for (int off = 1; off < T_; off <<= 1) {
            int v = (n >= off) ? arr[n - off] : 0;
            __syncthreads();
            if (v > arr[n]) arr[n] = v;
            __syncthreads();
        }
        lastdone[b * T_ + n] = arr[n];
        if (n == 0) {
            firstdone[b] = firstsh;
            delta[b] = (firstsh == T_) ? 1.f : 0.f;
        }
    }
}

// ---------------- Projection GEMM via MFMA, barrier-free K loop -------------
// [16384,256] f32 @ Wt^T (bf16) -> [16384,64] f32. grid (256, 3), block 256.
// A fragments loaded straight from global (32B/lane contiguous), cvt in-reg.
__global__ __launch_bounds__(256) void proj_mfma(
    const float* __restrict__ key_in, const float* __restrict__ query,
    const float* __restrict__ value, const short* __restrict__ wt,
    float* __restrict__ qp, float* __restrict__ kp, float* __restrict__ vp)
{
    const int mat = blockIdx.y;
    const float* A; float* O;
    if (mat == 0)      { A = query;  O = qp; }
    else if (mat == 1) { A = key_in; O = kp; }
    else               { A = value;  O = vp; }

    __shared__ short Wt[64][264];  // [d][k]; row stride 528B -> 2-way banks (free)

    const int t    = threadIdx.x;
    const int row0 = blockIdx.x * 64;
    const int lane = t & 63;
    const int mt   = t >> 6;       // wave id = m-tile
    const int lr   = lane & 15;
    const int lg   = lane >> 4;

    const short* wsrc = wt + (size_t)mat * (H_ * E_);
#pragma unroll
    for (int pass = 0; pass < 8; ++pass) {
        int idx = pass * 2048 + t * 8;
        int d = idx >> 8, k = idx & 255;
        *(bf16x8*)&Wt[d][k] = *(const bf16x8*)&wsrc[idx];
    }
    __syncthreads();

    const float* arow = &A[(size_t)(row0 + mt * 16 + lr) * E_ + lg * 8];

    f32x4 acc[4] = {};
#pragma unroll
    for (int kc = 0; kc < 8; ++kc) {
        f32x4 x0 = *(const f32x4*)(arow + kc * 32);
        f32x4 x1 = *(const f32x4*)(arow + kc * 32 + 4);
        bf16x8 af;
        af[0] = f2bf(x0[0]); af[1] = f2bf(x0[1]);
        af[2] = f2bf(x0[2]); af[3] = f2bf(x0[3]);
        af[4] = f2bf(x1[0]); af[5] = f2bf(x1[1]);
        af[6] = f2bf(x1[2]); af[7] = f2bf(x1[3]);
#pragma unroll
        for (int nt = 0; nt < 4; ++nt) {
            bf16x8 bfrag = *(const bf16x8*)&Wt[nt * 16 + lr][kc * 32 + lg * 8];
            acc[nt] = __builtin_amdgcn_mfma_f32_16x16x32_bf16(af, bfrag, acc[nt], 0, 0, 0);
        }
    }

#pragma unroll
    for (int nt = 0; nt < 4; ++nt)
#pragma unroll
        for (int i = 0; i < 4; ++i)
            O[(size_t)(row0 + mt * 16 + lg * 4 + i) * H_ + nt * 16 + lr] = acc[nt][i];
}

// ---------------- out0 (blocks < B*T) + next_h (blocks >= B*T) --------------
__global__ __launch_bounds__(256) void out_kernel(
    const float* __restrict__ qp, const float* __restrict__ kp,
    const float* __restrict__ vp, const float* __restrict__ hs,
    const int* __restrict__ lastdone, const int* __restrict__ firstdone,
    const float* __restrict__ delta,
    float* __restrict__ out0, float* __restrict__ outh)
{
    if (blockIdx.x < B_ * T_) {
        const int n  = blockIdx.x & (T_ - 1);
        const int b  = blockIdx.x >> 9;
        const int ca = threadIdx.x >> 6;
        const int d  = threadIdx.x & 63;
        const int c  = NA * n + ca;

        const float* kb = kp + (size_t)b * C_ * H_;
        const float* vb = vp + (size_t)b * C_ * H_;
        const float qv  = qp[((size_t)b * C_ + c) * H_ + d];

        float acc = 0.f;
        for (int ma = 0; ma <= ca; ++ma) {
            int m = NA * n + ma;
            float prod = qv * kb[(size_t)m * H_ + d];
#pragma unroll
            for (int off = 32; off; off >>= 1) prod += __shfl_xor(prod, off);
            acc += prod * vb[(size_t)m * H_ + d];
        }
        const int s = lastdone[b * T_ + n];
        float decay = KAPPA;
        for (int mt = n - 1; mt >= s; --mt) {
#pragma unroll
            for (int ma = 0; ma < NA; ++ma) {
                int m = NA * mt + ma;
                float prod = qv * kb[(size_t)m * H_ + d];
#pragma unroll
                for (int off = 32; off; off >>= 1) prod += __shfl_xor(prod, off);
                acc += decay * prod * vb[(size_t)m * H_ + d];
            }
            decay *= KAPPA;
        }
        if (n < firstdone[b]) {
            float cacc = 0.f;
            const float* hsb = hs + (size_t)b * H_ * H_;
#pragma unroll
            for (int h = 0; h < H_; ++h) {
                float qh = __shfl(qv, h);
                cacc += qh * hsb[h * H_ + d];
            }
            acc += powf(KAPPA, (float)(n + 1)) * cacc;
        }
        out0[((size_t)b * C_ + c) * H_ + d] = acc;
    } else {
        // next_h: 4 (b,h) pairs per block, wave = one h
        const int pair = (blockIdx.x - B_ * T_) * 4 + (threadIdx.x >> 6);
        const int h = pair & (H_ - 1);
        const int b = pair >> 6;
        const int d = threadIdx.x & 63;
        const int s = lastdone[b * T_ + (T_ - 1)];
        const float* kb = kp + (size_t)b * C_ * H_;
        const float* vb = vp + (size_t)b * C_ * H_;

        float acc = 0.f;
        float w = 1.f;
        for (int mt = T_ - 1; mt >= s; --mt) {
#pragma unroll
            for (int ma = 0; ma < NA; ++ma) {
                int m = NA * mt + ma;
                acc += w * kb[(size_t)m * H_ + h] * vb[(size_t)m * H_ + d];
            }
            w *= KAPPA;
        }
        acc += hs[(size_t)b * H_ * H_ + h * H_ + d] * powf(KAPPA, (float)T_) * delta[b];
        outh[(size_t)b * H_ * H_ + h * H_ + d] = acc;
    }
}

extern "C" void kernel_launch(void* const* d_in, const int* in_sizes, int n_in,
                              void* d_out, int out_size, void* d_ws, size_t ws_size,
                              hipStream_t stream)
{
    const float* key_in = (const float*)d_in[0];
    const float* query  = (const float*)d_in[1];
    const float* value  = (const float*)d_in[2];
    const float* hstate = (const float*)d_in[3];
    const unsigned char* dones = (const unsigned char*)d_in[4];
    const float* w_q = (const float*)d_in[5];
    const float* w_k = (const float*)d_in[6];
    const float* w_v = (const float*)d_in[7];

    float* qp = (float*)d_ws;
    float* kp = qp + (size_t)B_ * C_ * H_;
    float* vp = kp + (size_t)B_ * C_ * H_;
    short* wt = (short*)(vp + (size_t)B_ * C_ * H_);
    int*   lastdone  = (int*)(wt + 3 * H_ * E_);
    int*   firstdone = lastdone + B_ * T_;
    float* delta     = (float*)(firstdone + B_);

    prep_kernel<<<20, 512, 0, stream>>>(w_q, w_k, w_v, wt, dones,
                                        lastdone, firstdone, delta);
    dim3 pgrid(B_ * C_ / 64, 3);
    proj_mfma<<<pgrid, 256, 0, stream>>>(key_in, query, value, wt, qp, kp, vp);
    out_kernel<<<B_ * T_ + B_ * H_ / 4, 256, 0, stream>>>(
        qp, kp, vp, hstate, lastdone, firstdone, delta,
        (float*)d_out, (float*)d_out + (size_t)B_ * C_ * H_);
}

// Round 4
// 32.682 us; speedup vs baseline: 6.3578x; 1.3228x over previous
//
#include <hip/hip_runtime.h>
#include <hip/hip_bf16.h>
#include <cstddef>

#define B_ 8
#define C_ 2048
#define E_ 256
#define H_ 64
#define T_ 512
#define NA 4
#define KAPPA 0.9f

typedef __attribute__((ext_vector_type(8))) short bf16x8;
typedef __attribute__((ext_vector_type(4))) float f32x4;

__device__ inline short f2bf(float x) {
    unsigned u = __builtin_bit_cast(unsigned, x);
    u += 0x7fff + ((u >> 16) & 1);   // RNE
    return (short)(u >> 16);
}

// ---------------- W transpose+convert: W[256][64] f32 -> Wt[64][256] bf16 ---
__global__ __launch_bounds__(256) void wt_kernel(
    const float* __restrict__ w_q, const float* __restrict__ w_k,
    const float* __restrict__ w_v, short* __restrict__ wt)
{
    const int mat = blockIdx.x >> 2;
    const int k0  = (blockIdx.x & 3) * 64;
    const float* W = (mat == 0) ? w_q : (mat == 1) ? w_k : w_v;
    __shared__ float tile[64][67];
    const int t = threadIdx.x;
#pragma unroll
    for (int pass = 0; pass < 16; ++pass) {
        int idx = pass * 256 + t;
        int r = idx >> 6, c = idx & 63;
        tile[r][c] = W[(size_t)(k0 + r) * H_ + c];
    }
    __syncthreads();
#pragma unroll
    for (int pass = 0; pass < 16; ++pass) {
        int idx = pass * 256 + t;
        int d = idx >> 6, c = idx & 63;
        wt[(size_t)mat * (H_ * E_) + (size_t)d * E_ + k0 + c] = f2bf(tile[c][d]);
    }
}

// ---------------- Projection GEMM via MFMA, barrier-free K loop -------------
__global__ __launch_bounds__(256) void proj_mfma(
    const float* __restrict__ key_in, const float* __restrict__ query,
    const float* __restrict__ value, const short* __restrict__ wt,
    float* __restrict__ qp, float* __restrict__ kp, float* __restrict__ vp)
{
    const int mat = blockIdx.y;
    const float* A; float* O;
    if (mat == 0)      { A = query;  O = qp; }
    else if (mat == 1) { A = key_in; O = kp; }
    else               { A = value;  O = vp; }

    __shared__ short Wt[64][264];  // row stride 528B -> 2-way banks (free)

    const int t    = threadIdx.x;
    const int row0 = blockIdx.x * 64;
    const int lane = t & 63;
    const int mt   = t >> 6;
    const int lr   = lane & 15;
    const int lg   = lane >> 4;

    const short* wsrc = wt + (size_t)mat * (H_ * E_);
#pragma unroll
    for (int pass = 0; pass < 8; ++pass) {
        int idx = pass * 2048 + t * 8;
        int d = idx >> 8, k = idx & 255;
        *(bf16x8*)&Wt[d][k] = *(const bf16x8*)&wsrc[idx];
    }
    __syncthreads();

    const float* arow = &A[(size_t)(row0 + mt * 16 + lr) * E_ + lg * 8];

    f32x4 acc[4] = {};
#pragma unroll
    for (int kc = 0; kc < 8; ++kc) {
        f32x4 x0 = *(const f32x4*)(arow + kc * 32);
        f32x4 x1 = *(const f32x4*)(arow + kc * 32 + 4);
        bf16x8 af;
        af[0] = f2bf(x0[0]); af[1] = f2bf(x0[1]);
        af[2] = f2bf(x0[2]); af[3] = f2bf(x0[3]);
        af[4] = f2bf(x1[0]); af[5] = f2bf(x1[1]);
        af[6] = f2bf(x1[2]); af[7] = f2bf(x1[3]);
#pragma unroll
        for (int nt = 0; nt < 4; ++nt) {
            bf16x8 bfrag = *(const bf16x8*)&Wt[nt * 16 + lr][kc * 32 + lg * 8];
            acc[nt] = __builtin_amdgcn_mfma_f32_16x16x32_bf16(af, bfrag, acc[nt], 0, 0, 0);
        }
    }

#pragma unroll
    for (int nt = 0; nt < 4; ++nt)
#pragma unroll
        for (int i = 0; i < 4; ++i)
            O[(size_t)(row0 + mt * 16 + lg * 4 + i) * H_ + nt * 16 + lr] = acc[nt][i];
}

// ---------------- out0 + next_h, wave-per-unit, inline dones scans ----------
// waves 0..4095: out0 for (b = idx>>9, n = idx&511); lane = (row a, dim grp g)
// waves 4096..4607: next_h for (b = pair>>6, h = pair&63); lane = d
__global__ __launch_bounds__(256) void out_kernel(
    const float* __restrict__ qp, const float* __restrict__ kp,
    const float* __restrict__ vp, const float* __restrict__ hs,
    const unsigned char* __restrict__ raw,
    float* __restrict__ out0, float* __restrict__ outh)
{
    const int t    = threadIdx.x;
    const int lane = t & 63;
    const int idx  = blockIdx.x * 4 + (t >> 6);

    // dones layout detection: bool(1B) vs int32(4B LE 0/1), via first 2KB
    const uint4* dp = (const uint4*)raw;
    uint4 w0 = dp[lane * 2];
    uint4 w1 = dp[lane * 2 + 1];
    unsigned nz = (w0.x | w0.y | w0.z | w0.w | w1.x | w1.y | w1.z | w1.w) & 0xFFFFFF00u;
    const int stride = (__ballot(nz != 0) != 0ULL) ? 1 : 4;

    if (idx < B_ * T_) {
        const int b = idx >> 9;
        const int n = idx & (T_ - 1);
        const int a = lane >> 4;
        const int g = lane & 15;
        const unsigned char* drow = raw + (size_t)b * C_ * stride;

        // backward ballot scan: s = last done timestep <= n (0 if none)
        int s = 0; bool found = false;
        for (int base = n; ; base -= 64) {
            int j = base - lane;
            unsigned long long m =
                __ballot(j >= 0 && drow[(size_t)(4 * j) * stride] != 0);
            if (m) { s = base - __builtin_ctzll(m); found = true; break; }
            if (base < 64) break;
        }

        const float* kb = kp + (size_t)b * C_ * H_;
        const float* vb = vp + (size_t)b * C_ * H_;
        f32x4 q4 = *(const f32x4*)&qp[((size_t)b * C_ + 4 * n + a) * H_ + 4 * g];

        f32x4 acc = {};
        // diagonal timestep: decay 1, causal mask ma <= a
#pragma unroll
        for (int ma = 0; ma < NA; ++ma) {
            const int m = 4 * n + ma;
            f32x4 k4 = *(const f32x4*)&kb[(size_t)m * H_ + 4 * g];
            float p = q4[0] * k4[0] + q4[1] * k4[1] + q4[2] * k4[2] + q4[3] * k4[3];
            p += __shfl_xor(p, 1); p += __shfl_xor(p, 2);
            p += __shfl_xor(p, 4); p += __shfl_xor(p, 8);
            if (ma <= a) {
                f32x4 v4 = *(const f32x4*)&vb[(size_t)m * H_ + 4 * g];
                acc[0] += p * v4[0]; acc[1] += p * v4[1];
                acc[2] += p * v4[2]; acc[3] += p * v4[3];
            }
        }
        // earlier timesteps in segment
        float decay = KAPPA;
        for (int mt = n - 1; mt >= s; --mt) {
#pragma unroll
            for (int ma = 0; ma < NA; ++ma) {
                const int m = 4 * mt + ma;
                f32x4 k4 = *(const f32x4*)&kb[(size_t)m * H_ + 4 * g];
                float p = q4[0] * k4[0] + q4[1] * k4[1] + q4[2] * k4[2] + q4[3] * k4[3];
                p += __shfl_xor(p, 1); p += __shfl_xor(p, 2);
                p += __shfl_xor(p, 4); p += __shfl_xor(p, 8);
                p *= decay;
                f32x4 v4 = *(const f32x4*)&vb[(size_t)m * H_ + 4 * g];
                acc[0] += p * v4[0]; acc[1] += p * v4[1];
                acc[2] += p * v4[2]; acc[3] += p * v4[3];
            }
            decay *= KAPPA;
        }
        // cross term (xi != 0 iff no done in [0, n])
        if (!found) {
            const float xi = powf(KAPPA, (float)(n + 1));
            const float* hsb = hs + (size_t)b * H_ * H_;
            f32x4 cacc = {};
#pragma unroll
            for (int h = 0; h < H_; ++h) {
                float qh = __shfl(q4[h & 3], (a << 4) + (h >> 2));
                f32x4 h4 = *(const f32x4*)&hsb[h * H_ + 4 * g];
                cacc[0] += qh * h4[0]; cacc[1] += qh * h4[1];
                cacc[2] += qh * h4[2]; cacc[3] += qh * h4[3];
            }
            acc[0] += xi * cacc[0]; acc[1] += xi * cacc[1];
            acc[2] += xi * cacc[2]; acc[3] += xi * cacc[3];
        }
        *(f32x4*)&out0[((size_t)b * C_ + 4 * n + a) * H_ + 4 * g] = acc;
    } else {
        const int pair = idx - B_ * T_;   // [0, 512)
        const int b = pair >> 6;
        const int h = pair & (H_ - 1);
        const int d = lane;
        const unsigned char* drow = raw + (size_t)b * C_ * stride;

        int s = 0; bool found = false;
        for (int base = T_ - 1; ; base -= 64) {
            int j = base - lane;
            unsigned long long m =
                __ballot(j >= 0 && drow[(size_t)(4 * j) * stride] != 0);
            if (m) { s = base - __builtin_ctzll(m); found = true; break; }
            if (base < 64) break;
        }

        const float* kb = kp + (size_t)b * C_ * H_;
        const float* vb = vp + (size_t)b * C_ * H_;
        float acc = 0.f, w = 1.f;
        for (int mt = T_ - 1; mt >= s; --mt) {
#pragma unroll
            for (int ma = 0; ma < NA; ++ma) {
                const int m = 4 * mt + ma;
                acc += w * kb[(size_t)m * H_ + h] * vb[(size_t)m * H_ + d];
            }
            w *= KAPPA;
        }
        if (!found)
            acc += hs[((size_t)b * H_ + h) * H_ + d] * powf(KAPPA, (float)T_);
        outh[((size_t)b * H_ + h) * H_ + d] = acc;
    }
}

extern "C" void kernel_launch(void* const* d_in, const int* in_sizes, int n_in,
                              void* d_out, int out_size, void* d_ws, size_t ws_size,
                              hipStream_t stream)
{
    const float* key_in = (const float*)d_in[0];
    const float* query  = (const float*)d_in[1];
    const float* value  = (const float*)d_in[2];
    const float* hstate = (const float*)d_in[3];
    const unsigned char* dones = (const unsigned char*)d_in[4];
    const float* w_q = (const float*)d_in[5];
    const float* w_k = (const float*)d_in[6];
    const float* w_v = (const float*)d_in[7];

    float* qp = (float*)d_ws;
    float* kp = qp + (size_t)B_ * C_ * H_;
    float* vp = kp + (size_t)B_ * C_ * H_;
    short* wt = (short*)(vp + (size_t)B_ * C_ * H_);

    wt_kernel<<<12, 256, 0, stream>>>(w_q, w_k, w_v, wt);
    dim3 pgrid(B_ * C_ / 64, 3);
    proj_mfma<<<pgrid, 256, 0, stream>>>(key_in, query, value, wt, qp, kp, vp);
    out_kernel<<<(B_ * T_ + B_ * H_) / 4, 256, 0, stream>>>(
        qp, kp, vp, hstate, dones,
        (float*)d_out, (float*)d_out + (size_t)B_ * C_ * H_);
}